// Round 13
// baseline (149.582 us; speedup 1.0000x reference)
//
#include <hip/hip_runtime.h>
#include <hip/hip_fp16.h>

#define BB 8
#define CC 64
#define HH 112
#define WW 112
#define HWs (HH * WW)                 // 12544
#define KEYN 9

// ---- conv_key v2 geometry: 256-px tile, 8px x 8out per thread ----
#define CK2_PX 256
#define CK2_TILES (HWs / CK2_PX)      // 49
#define CK2_NBLK (BB * CK2_TILES)     // 392
#define WTS 68                        // Wt row stride: 16B-aligned rows

// ---- fused sampler geometry ----
#define SM_PX 32
#define SM_TILES (HWs / SM_PX)        // 392
#define SM_NBLK (BB * SM_TILES)       // 3136

// fused-kernel LDS float offsets (phase overlays):
//   phase A (stage+conv):   Wq[64][20] @0, Sb[20] @1280, L[32][21] @1300,
//                           Xq[64][32] @1972 (end 4020)
//   phase B (softmax):      Pf float4 [288] @0 (overlays dead Wq)
//   phase C (sampling):     T2 [32px][9k][4corner]{addr,wgt} @0 (2304 f,
//                           overlays Pf/L/Xq-start), OutT[32][68] @2304
#define OFF_WQ   0
#define OFF_SB   1280
#define OFF_L    1300
#define OFF_XQ   1972
#define OFF_P    0
#define OFF_T    0
#define OFF_OUTT 2304
#define SM_LDS   4480                 // 17.92 KB

typedef int v4i __attribute__((ext_vector_type(4)));

// forced-MLP gather: result register is bound by asm -> must stay live
#define GLOAD(dst, p) asm volatile("global_load_dwordx4 %0, %1, off" \
                                   : "=&v"(dst) : "v"(p))

// xor lane swaps within 32-lane halves (BitMode: offset=(xor<<10)|0x1F)
__device__ __forceinline__ float swzx16(float v) {
    return __uint_as_float(__builtin_amdgcn_ds_swizzle(__float_as_uint(v), 0x401F));
}
__device__ __forceinline__ float swzx8(float v) {
    return __uint_as_float(__builtin_amdgcn_ds_swizzle(__float_as_uint(v), 0x201F));
}

// ---------------------------------------------------------------------------
// conv_key v2, LINEAR mapping (11 us measured R8) + NON-TEMPORAL Kf stores
// (via clang ext_vector v4i — HIP int4 is a class type the builtin rejects,
// R12 compile fail). Theory: R8's +9.5us sampler regression was cross-XCD
// coherence on lines left DIRTY in writer XCDs' L2; nt stores write through
// without dirty copies, so the batch-pinned sampler fills CLEAN from L3
// (12.8 MB compulsory, amortized over 36x reuse) — keeping conv's linear
// speed AND the sampler's 42us.
// ---------------------------------------------------------------------------
__global__ __launch_bounds__(256, 4) void conv_key_kernel(
    const float* __restrict__ key, const float* __restrict__ w_refer,
    const float* __restrict__ b_refer, __half* __restrict__ Kf)
{
    __shared__ float Wt[64 * WTS];        // 17.4 KB
    __shared__ float Xin[16 * CK2_PX];    // 16 KB (one k-chunk)

    const int t = threadIdx.x;
    const int blk = blockIdx.x;
    const int b = blk / CK2_TILES;               // LINEAR mapping
    const int s0 = (blk - b * CK2_TILES) * CK2_PX;
    const size_t inb = (size_t)b * CC * HWs + s0;

    // ---- stage transposed weights Wt[k][o] (once)
    #pragma unroll
    for (int m = 0; m < 4; ++m) {
        const int f = t + 256 * m;
        const int o = f >> 4;
        const int q = f & 15;
        const float4 wv = *reinterpret_cast<const float4*>(w_refer + o * CC + 4 * q);
        Wt[(4 * q + 0) * WTS + o] = wv.x;
        Wt[(4 * q + 1) * WTS + o] = wv.y;
        Wt[(4 * q + 2) * WTS + o] = wv.z;
        Wt[(4 * q + 3) * WTS + o] = wv.w;
    }
    // ---- stage k-chunk 0: Xin[kr][256], coalesced rows
    #pragma unroll
    for (int m = 0; m < 4; ++m) {
        const int f = t + 256 * m;
        const int kr = f >> 6;               // 0..15
        const int c4 = (f & 63) * 4;         // 0..252
        *reinterpret_cast<float4*>(&Xin[kr * CK2_PX + c4]) =
            *reinterpret_cast<const float4*>(key + inb + (size_t)kr * HWs + c4);
    }
    __syncthreads();

    const int og = t & 7;     // 8 outputs: og*8..og*8+7
    const int pg = t >> 3;    // 8 pixels:  pg*8..pg*8+7

    float acc[8][8];
    {
        const float4 b0 = *reinterpret_cast<const float4*>(b_refer + 8 * og);
        const float4 b1 = *reinterpret_cast<const float4*>(b_refer + 8 * og + 4);
        #pragma unroll
        for (int pi = 0; pi < 8; ++pi) {
            acc[pi][0] = b0.x; acc[pi][1] = b0.y; acc[pi][2] = b0.z; acc[pi][3] = b0.w;
            acc[pi][4] = b1.x; acc[pi][5] = b1.y; acc[pi][6] = b1.z; acc[pi][7] = b1.w;
        }
    }

    float4 pf[4];
    #pragma unroll
    for (int kc = 0; kc < 4; ++kc) {
        // issue next chunk's global loads EARLY (hide under FMA block)
        if (kc < 3) {
            #pragma unroll
            for (int m = 0; m < 4; ++m) {
                const int f = t + 256 * m;
                const int kr = f >> 6;
                const int c4 = (f & 63) * 4;
                pf[m] = *reinterpret_cast<const float4*>(
                    key + inb + (size_t)((kc + 1) * 16 + kr) * HWs + c4);
            }
        }
        // compute 16 k from the staged chunk
        #pragma unroll 4
        for (int kk = 0; kk < 16; ++kk) {
            const float4 a0 = *reinterpret_cast<const float4*>(&Xin[kk * CK2_PX + pg * 8]);
            const float4 a1 = *reinterpret_cast<const float4*>(&Xin[kk * CK2_PX + pg * 8 + 4]);
            const int k = kc * 16 + kk;
            const float4 w0 = *reinterpret_cast<const float4*>(&Wt[k * WTS + og * 8]);
            const float4 w1 = *reinterpret_cast<const float4*>(&Wt[k * WTS + og * 8 + 4]);
            const float av[8] = {a0.x, a0.y, a0.z, a0.w, a1.x, a1.y, a1.z, a1.w};
            const float wv[8] = {w0.x, w0.y, w0.z, w0.w, w1.x, w1.y, w1.z, w1.w};
            #pragma unroll
            for (int pi = 0; pi < 8; ++pi) {
                #pragma unroll
                for (int oj = 0; oj < 8; ++oj)
                    acc[pi][oj] = fmaf(av[pi], wv[oj], acc[pi][oj]);
            }
        }
        __syncthreads();                 // all reads of this chunk done
        if (kc < 3) {
            #pragma unroll
            for (int m = 0; m < 4; ++m) {
                const int f = t + 256 * m;
                const int kr = f >> 6;
                const int c4 = (f & 63) * 4;
                *reinterpret_cast<float4*>(&Xin[kr * CK2_PX + c4]) = pf[m];
            }
            __syncthreads();             // next chunk visible
        }
    }

    // ---- fp16 pack + NON-TEMPORAL store (no dirty L2 copies; sampler
    // fills clean from L3). Per pixel 16B, 128B contiguous per og-group.
    #pragma unroll
    for (int pi = 0; pi < 8; ++pi) {
        const size_t ob = ((size_t)b * HWs + s0 + pg * 8 + pi) * CC + 8 * og; // halfs
        union { __half2 h; int i; } u0, u1, u2, u3;
        u0.h = __floats2half2_rn(acc[pi][0], acc[pi][1]);
        u1.h = __floats2half2_rn(acc[pi][2], acc[pi][3]);
        u2.h = __floats2half2_rn(acc[pi][4], acc[pi][5]);
        u3.h = __floats2half2_rn(acc[pi][6], acc[pi][7]);
        v4i pk;
        pk.x = u0.i; pk.y = u1.i; pk.z = u2.i; pk.w = u3.i;
        __builtin_nontemporal_store(pk, reinterpret_cast<v4i*>(Kf + ob));
    }
}

// ---------------------------------------------------------------------------
// Bilinear data for (p,k): row bases, x0, 4 pre-multiplied corner weights.
// ---------------------------------------------------------------------------
struct TEnt { float4 a, b; };

__device__ __forceinline__ TEnt make_entry2(int e, float4 pk, int s0)
{
    const int p = e & 31;
    const int s = s0 + p;
    const int yi = s / WW;
    const int xi = s - yi * WW;
    const float py  = pk.y + (float)yi;
    const float pxf = pk.z + (float)xi;
    const float fy = floorf(py), fx = floorf(pxf);
    const float wy1 = py - fy, wx1 = pxf - fx;
    const float wy0 = 1.f - wy1, wx0 = 1.f - wx1;
    const int ix0 = (int)fx;
    const int iy0 = (int)fy, iy1 = iy0 + 1;
    const float vx0 = (ix0 >= 0 && ix0 < WW)      ? 1.f : 0.f;
    const float vx1 = (ix0 >= -1 && ix0 < WW - 1) ? 1.f : 0.f;
    const float vy0 = (iy0 >= 0 && iy0 < HH)      ? 1.f : 0.f;
    const float vy1 = (iy1 >= 0 && iy1 < HH)      ? 1.f : 0.f;
    const int yc0 = min(max(iy0, 0), HH - 1);
    const int yc1 = min(max(iy1, 0), HH - 1);
    TEnt r;
    r.a.x = __uint_as_float((unsigned)(yc0 * WW * 128));
    r.a.y = __uint_as_float((unsigned)(yc1 * WW * 128));
    r.a.z = __int_as_float(ix0);
    r.a.w = 0.f;
    const float ay0 = pk.x * wy0 * vy0;
    const float ay1 = pk.x * wy1 * vy1;
    r.b.x = ay0 * wx0 * vx0;
    r.b.y = ay0 * wx1 * vx1;
    r.b.z = ay1 * wx0 * vx0;
    r.b.w = ay1 * wx1 * vx1;
    return r;
}

// ---------------------------------------------------------------------------
// Fused (R6 drain structure, proven 41.8-42.0us with clean/local Kf):
// query conv -> softmax -> pre-selected corner table -> 9-deep forced
// gather cluster per round (asm loads, vmcnt(0), fence, consume).
// ---------------------------------------------------------------------------
__global__ __launch_bounds__(256, 4) void fused_sample_kernel(
    const float* __restrict__ query, const float* __restrict__ w_attn,
    const float* __restrict__ b_attn, const float* __restrict__ w_off,
    const float* __restrict__ b_off, const __half* __restrict__ Kf,
    float* __restrict__ out)
{
    __shared__ float S[SM_LDS];
    float*  Wq   = S + OFF_WQ;     // [64][20]
    float*  Sb   = S + OFF_SB;     // [20]
    float*  L    = S + OFF_L;      // [32][21]
    float*  Xq   = S + OFF_XQ;     // [64][32]
    float4* Pf4  = reinterpret_cast<float4*>(S + OFF_P);   // [288] {a,dy,dx,-}
    float*  Tb   = S + OFF_T;      // T2: 288 (p,k) x 4 corners x {addr,wgt}
    float*  OutT = S + OFF_OUTT;   // [32][68]

    const int t = threadIdx.x;
    const int l = t & 63;
    const int w = t >> 6;
    const int blk = blockIdx.x;
    const int b = blk & 7;                       // batch == XCD round-robin
    const int tile = blk >> 3;
    const int s0 = tile * SM_PX;
    const size_t qb = (size_t)b * CC * HWs + s0;
    const char* Kfb = reinterpret_cast<const char*>(Kf) + (size_t)b * HWs * 128;

    // ---- stage transposed query weights [k][20] + biases + query tile
    for (int f = t; f < 304; f += 256) {
        const int r = f >> 4;
        const int q = f & 15;
        const float* src = (r < KEYN) ? (w_attn + r * CC) : (w_off + (r - KEYN) * CC);
        const float4 wv = *reinterpret_cast<const float4*>(src + 4 * q);
        Wq[(4 * q + 0) * 20 + r] = wv.x;
        Wq[(4 * q + 1) * 20 + r] = wv.y;
        Wq[(4 * q + 2) * 20 + r] = wv.z;
        Wq[(4 * q + 3) * 20 + r] = wv.w;
    }
    if (t < 64) Wq[t * 20 + 19] = 0.f;
    if (t < 20) Sb[t] = (t < KEYN) ? b_attn[t] : (t < 19 ? b_off[t - KEYN] : 0.f);
    #pragma unroll
    for (int m = 0; m < 2; ++m) {
        const int f = t + 256 * m;          // 0..511
        const int c = f >> 3;                // 0..63
        const int p4 = (f & 7) * 4;          // 0..28
        *reinterpret_cast<float4*>(&Xq[c * 32 + p4]) =
            *reinterpret_cast<const float4*>(query + qb + (size_t)c * HWs + p4);
    }
    __syncthreads();

    // ---- query conv: thread = (px = t&31, og = t>>5 < 5); input from LDS
    {
        const int px = t & 31;
        const int og = t >> 5;
        if (og < 5) {
            const int o4 = 4 * og;
            float4 acc = *reinterpret_cast<const float4*>(&Sb[o4]);
            #pragma unroll 8
            for (int k = 0; k < 64; ++k) {
                const float a = Xq[k * 32 + px];
                const float4 wv = *reinterpret_cast<const float4*>(&Wq[k * 20 + o4]);
                acc.x = fmaf(a, wv.x, acc.x);
                acc.y = fmaf(a, wv.y, acc.y);
                acc.z = fmaf(a, wv.z, acc.z);
                acc.w = fmaf(a, wv.w, acc.w);
            }
            L[px * 21 + o4 + 0] = acc.x;
            L[px * 21 + o4 + 1] = acc.y;
            L[px * 21 + o4 + 2] = acc.z;
            L[px * 21 + o4 + 3] = acc.w;
        }
    }
    __syncthreads();

    // ---- softmax + pack Pf[k*32+px] = {attn, dy, dx, 0} (overlays dead Wq)
    if (t < SM_PX) {
        float lg[KEYN], of[10];
        #pragma unroll
        for (int k = 0; k < KEYN; ++k) lg[k] = L[t * 21 + k];
        #pragma unroll
        for (int j = 0; j < 10; ++j) of[j] = L[t * 21 + KEYN + j];
        float m = lg[0];
        #pragma unroll
        for (int k = 1; k < KEYN; ++k) m = fmaxf(m, lg[k]);
        float s = 0.f, e[KEYN];
        #pragma unroll
        for (int k = 0; k < KEYN; ++k) { e[k] = expf(lg[k] - m); s += e[k]; }
        const float sinv = 1.0f / s;
        #pragma unroll
        for (int k = 0; k < KEYN; ++k)
            Pf4[k * 32 + t] = make_float4(e[k] * sinv, of[k], of[k + 1], 0.f);
    }
    __syncthreads();

    // ---- build T2: entry e = k*32+p -> 4 corner records at float index
    // (p*9+k)*8 + corner*2: {addr = rowbase + clamp(x0+c2)*128, wgt}.
    {
        const float4 q1 = Pf4[t];
        float4 q2 = make_float4(0.f, 0.f, 0.f, 0.f);
        if (t < 32) q2 = Pf4[256 + t];
        __syncthreads();
        #pragma unroll
        for (int m = 0; m < 2; ++m) {
            const int e = (m == 0) ? t : (256 + t);
            if (m == 1 && t >= 32) break;
            const TEnt en = make_entry2(e, (m == 0) ? q1 : q2, s0);
            const int p = e & 31, k = e >> 5;
            const int x0 = __float_as_int(en.a.z);
            const unsigned xc0 = (unsigned)(min(max(x0, 0), WW - 1)) << 7;
            const unsigned xc1 = (unsigned)(min(max(x0 + 1, 0), WW - 1)) << 7;
            const unsigned rb0 = __float_as_uint(en.a.x);
            const unsigned rb1 = __float_as_uint(en.a.y);
            float4 r0, r1;
            r0.x = __uint_as_float(rb0 + xc0); r0.y = en.b.x;   // (y0,x0)
            r0.z = __uint_as_float(rb0 + xc1); r0.w = en.b.y;   // (y0,x1)
            r1.x = __uint_as_float(rb1 + xc0); r1.y = en.b.z;   // (y1,x0)
            r1.z = __uint_as_float(rb1 + xc1); r1.w = en.b.w;   // (y1,x1)
            float* dst = Tb + (p * 9 + k) * 8;
            *reinterpret_cast<float4*>(dst)     = r0;
            *reinterpret_cast<float4*>(dst + 4) = r1;
        }
    }
    __syncthreads();

    // ---- sampling: wave w -> px [8w,8w+8) as 4 rounds of a pixel pair.
    // Lane = (sub=l>>5 pixel, corner=(l>>3)&3, ch8=l&7).
    const int  ch8  = l & 7;                  // 8-channel chunk
    const int  corf = ((l >> 3) & 3) * 2;     // corner float offset in T2
    const int  sub  = l >> 5;                 // which pixel of the pair
    const char* KfbC = Kfb + (unsigned)(ch8 * 16);

    for (int j = 0; j < 4; ++j) {
        const int p = w * 8 + 2 * j + sub;
        const float* Te = Tb + p * 72 + corf;     // + k*8 per key

        // 9 broadcast b64 reads: {addr, wgt} per (p,k,corner)
        float2 tw[KEYN];
        #pragma unroll
        for (int k = 0; k < KEYN; ++k)
            tw[k] = *reinterpret_cast<const float2*>(Te + k * 8);

        // 9 forced-cluster gathers (16B each); all dests live at the wait
        v4i rr[KEYN];
        #pragma unroll
        for (int k = 0; k < KEYN; ++k)
            GLOAD(rr[k], KfbC + __float_as_uint(tw[k].x));
        asm volatile("s_waitcnt vmcnt(0)" ::: "memory");
        __builtin_amdgcn_sched_barrier(0);

        float acc[8] = {0.f, 0.f, 0.f, 0.f, 0.f, 0.f, 0.f, 0.f};
        #pragma unroll
        for (int k = 0; k < KEYN; ++k) {
            const float wgt = tw[k].y;
            union { int i; __half2 h; } u0, u1, u2, u3;
            u0.i = rr[k][0]; u1.i = rr[k][1]; u2.i = rr[k][2]; u3.i = rr[k][3];
            acc[0] = fmaf(__low2float(u0.h),  wgt, acc[0]);
            acc[1] = fmaf(__high2float(u0.h), wgt, acc[1]);
            acc[2] = fmaf(__low2float(u1.h),  wgt, acc[2]);
            acc[3] = fmaf(__high2float(u1.h), wgt, acc[3]);
            acc[4] = fmaf(__low2float(u2.h),  wgt, acc[4]);
            acc[5] = fmaf(__high2float(u2.h), wgt, acc[5]);
            acc[6] = fmaf(__low2float(u3.h),  wgt, acc[6]);
            acc[7] = fmaf(__high2float(u3.h), wgt, acc[7]);
        }

        // fold y-corner pairs (lane^16), then x-corner pairs (lane^8)
        #pragma unroll
        for (int i = 0; i < 8; ++i) acc[i] += swzx16(acc[i]);
        #pragma unroll
        for (int i = 0; i < 8; ++i) acc[i] += swzx8(acc[i]);

        if ((l & 24) == 0) {
            float* d = OutT + p * 68 + ch8 * 8;
            *reinterpret_cast<float4*>(d)     = make_float4(acc[0], acc[1], acc[2], acc[3]);
            *reinterpret_cast<float4*>(d + 4) = make_float4(acc[4], acc[5], acc[6], acc[7]);
        }
    }
    __syncthreads();

    // ---- transposed store: out[b][c][s0+px]
    const size_t ob = (size_t)b * CC * HWs + s0;
    #pragma unroll
    for (int m = 0; m < 8; ++m) {
        const int f = t + 256 * m;
        const int c = f >> 5;
        const int px = f & 31;
        out[ob + (size_t)c * HWs + px] = OutT[px * 68 + c];
    }
}

extern "C" void kernel_launch(void* const* d_in, const int* in_sizes, int n_in,
                              void* d_out, int out_size, void* d_ws, size_t ws_size,
                              hipStream_t stream)
{
    const float* query   = (const float*)d_in[0];
    const float* key     = (const float*)d_in[1];
    const float* w_refer = (const float*)d_in[2];
    const float* b_refer = (const float*)d_in[3];
    const float* w_attn  = (const float*)d_in[4];
    const float* b_attn  = (const float*)d_in[5];
    const float* w_off   = (const float*)d_in[6];
    const float* b_off   = (const float*)d_in[7];
    float* out = (float*)d_out;

    __half* Kf = (__half*)d_ws;   // [B*HW][64] pixel-major fp16, 12.8 MB

    hipLaunchKernelGGL(conv_key_kernel, dim3(CK2_NBLK), dim3(256), 0, stream,
                       key, w_refer, b_refer, Kf);
    hipLaunchKernelGGL(fused_sample_kernel, dim3(SM_NBLK), dim3(256), 0, stream,
                       query, w_attn, b_attn, w_off, b_off, Kf, out);
}

// Round 14
// 148.733 us; speedup vs baseline: 1.0057x; 1.0057x over previous
//
#include <hip/hip_runtime.h>
#include <hip/hip_fp16.h>

#define BB 8
#define CC 64
#define HH 112
#define WW 112
#define HWs (HH * WW)                 // 12544
#define KEYN 9

// ---- conv_key v2 geometry: 256-px tile, 8px x 8out per thread ----
#define CK2_PX 256
#define CK2_TILES (HWs / CK2_PX)      // 49
#define CK2_NBLK (BB * CK2_TILES)     // 392
#define WTS 68                        // Wt row stride: 16B-aligned rows

// ---- fused sampler geometry: 64-px tiles (prologue amortization) ----
#define SM_PX 64
#define SM_TILES (HWs / SM_PX)        // 196
#define SM_NBLK (BB * SM_TILES)       // 1568

// fused-kernel LDS float offsets (phase overlays):
//   phase A (stage+conv):   Wq[64][20] @0, Sb[20] @1280, L[64][21] @1300
//                           (end 2644), Xq[64][64] @2644 (end 6740)
//   phase B (softmax):      Pf float4 [576] @2644 (overlays dead Xq,
//                           2304 f -> end 4948; L stays live below)
//   phase C (sampling):     T2 [64px][9k][4corner]{addr,wgt} @0 (4608 f,
//                           overlays Wq/Sb/L + Pf after reg-read barrier),
//                           OutT[64][68] @4608 (end 8960)
#define OFF_WQ   0
#define OFF_SB   1280
#define OFF_L    1300
#define OFF_XQ   2644
#define OFF_P    2644
#define OFF_T    0
#define OFF_OUTT 4608
#define SM_LDS   8960                 // 35.84 KB -> 4 blocks/CU (143 KB)

typedef int v4i __attribute__((ext_vector_type(4)));

// forced-MLP gather: result register is bound by asm -> must stay live
#define GLOAD(dst, p) asm volatile("global_load_dwordx4 %0, %1, off" \
                                   : "=&v"(dst) : "v"(p))

// xor lane swaps within 32-lane halves (BitMode: offset=(xor<<10)|0x1F)
__device__ __forceinline__ float swzx16(float v) {
    return __uint_as_float(__builtin_amdgcn_ds_swizzle(__float_as_uint(v), 0x401F));
}
__device__ __forceinline__ float swzx8(float v) {
    return __uint_as_float(__builtin_amdgcn_ds_swizzle(__float_as_uint(v), 0x201F));
}

// ---------------------------------------------------------------------------
// conv_key v2 (register-blocked) + BATCH-PINNED mapping (b = blk&7): batch
// == XCD, so batch b's Kf lines are dirty in XCD b's L2 and the (also
// pinned) sampler reads 100% locally. R6/R8/R9/R13 quantified the
// coherence conservation: pinned 19.2+42.0 < linear 11.1+51.4 <
// linear+nt 21.4+43.0 — pinned is the best of the three.
// ---------------------------------------------------------------------------
__global__ __launch_bounds__(256, 4) void conv_key_kernel(
    const float* __restrict__ key, const float* __restrict__ w_refer,
    const float* __restrict__ b_refer, __half* __restrict__ Kf)
{
    __shared__ float Wt[64 * WTS];        // 17.4 KB
    __shared__ float Xin[16 * CK2_PX];    // 16 KB (one k-chunk)

    const int t = threadIdx.x;
    const int blk = blockIdx.x;
    const int b = blk & 7;                       // batch == XCD round-robin
    const int s0 = (blk >> 3) * CK2_PX;
    const size_t inb = (size_t)b * CC * HWs + s0;

    // ---- stage transposed weights Wt[k][o] (once)
    #pragma unroll
    for (int m = 0; m < 4; ++m) {
        const int f = t + 256 * m;
        const int o = f >> 4;
        const int q = f & 15;
        const float4 wv = *reinterpret_cast<const float4*>(w_refer + o * CC + 4 * q);
        Wt[(4 * q + 0) * WTS + o] = wv.x;
        Wt[(4 * q + 1) * WTS + o] = wv.y;
        Wt[(4 * q + 2) * WTS + o] = wv.z;
        Wt[(4 * q + 3) * WTS + o] = wv.w;
    }
    // ---- stage k-chunk 0: Xin[kr][256], coalesced rows
    #pragma unroll
    for (int m = 0; m < 4; ++m) {
        const int f = t + 256 * m;
        const int kr = f >> 6;               // 0..15
        const int c4 = (f & 63) * 4;         // 0..252
        *reinterpret_cast<float4*>(&Xin[kr * CK2_PX + c4]) =
            *reinterpret_cast<const float4*>(key + inb + (size_t)kr * HWs + c4);
    }
    __syncthreads();

    const int og = t & 7;     // 8 outputs: og*8..og*8+7
    const int pg = t >> 3;    // 8 pixels:  pg*8..pg*8+7

    float acc[8][8];
    {
        const float4 b0 = *reinterpret_cast<const float4*>(b_refer + 8 * og);
        const float4 b1 = *reinterpret_cast<const float4*>(b_refer + 8 * og + 4);
        #pragma unroll
        for (int pi = 0; pi < 8; ++pi) {
            acc[pi][0] = b0.x; acc[pi][1] = b0.y; acc[pi][2] = b0.z; acc[pi][3] = b0.w;
            acc[pi][4] = b1.x; acc[pi][5] = b1.y; acc[pi][6] = b1.z; acc[pi][7] = b1.w;
        }
    }

    float4 pf[4];
    #pragma unroll
    for (int kc = 0; kc < 4; ++kc) {
        // issue next chunk's global loads EARLY (hide under FMA block)
        if (kc < 3) {
            #pragma unroll
            for (int m = 0; m < 4; ++m) {
                const int f = t + 256 * m;
                const int kr = f >> 6;
                const int c4 = (f & 63) * 4;
                pf[m] = *reinterpret_cast<const float4*>(
                    key + inb + (size_t)((kc + 1) * 16 + kr) * HWs + c4);
            }
        }
        // compute 16 k from the staged chunk
        #pragma unroll 4
        for (int kk = 0; kk < 16; ++kk) {
            const float4 a0 = *reinterpret_cast<const float4*>(&Xin[kk * CK2_PX + pg * 8]);
            const float4 a1 = *reinterpret_cast<const float4*>(&Xin[kk * CK2_PX + pg * 8 + 4]);
            const int k = kc * 16 + kk;
            const float4 w0 = *reinterpret_cast<const float4*>(&Wt[k * WTS + og * 8]);
            const float4 w1 = *reinterpret_cast<const float4*>(&Wt[k * WTS + og * 8 + 4]);
            const float av[8] = {a0.x, a0.y, a0.z, a0.w, a1.x, a1.y, a1.z, a1.w};
            const float wv[8] = {w0.x, w0.y, w0.z, w0.w, w1.x, w1.y, w1.z, w1.w};
            #pragma unroll
            for (int pi = 0; pi < 8; ++pi) {
                #pragma unroll
                for (int oj = 0; oj < 8; ++oj)
                    acc[pi][oj] = fmaf(av[pi], wv[oj], acc[pi][oj]);
            }
        }
        __syncthreads();                 // all reads of this chunk done
        if (kc < 3) {
            #pragma unroll
            for (int m = 0; m < 4; ++m) {
                const int f = t + 256 * m;
                const int kr = f >> 6;
                const int c4 = (f & 63) * 4;
                *reinterpret_cast<float4*>(&Xin[kr * CK2_PX + c4]) = pf[m];
            }
            __syncthreads();             // next chunk visible
        }
    }

    // ---- fp16 pack + store: per pixel 16B (8 outs), 128B contiguous per
    // 8-lane og-group, 8 segments/wave
    #pragma unroll
    for (int pi = 0; pi < 8; ++pi) {
        const size_t ob = ((size_t)b * HWs + s0 + pg * 8 + pi) * CC + 8 * og; // halfs
        union { __half2 h; int i; } u0, u1, u2, u3;
        u0.h = __floats2half2_rn(acc[pi][0], acc[pi][1]);
        u1.h = __floats2half2_rn(acc[pi][2], acc[pi][3]);
        u2.h = __floats2half2_rn(acc[pi][4], acc[pi][5]);
        u3.h = __floats2half2_rn(acc[pi][6], acc[pi][7]);
        int4 pk; pk.x = u0.i; pk.y = u1.i; pk.z = u2.i; pk.w = u3.i;
        *reinterpret_cast<int4*>(Kf + ob) = pk;
    }
}

// ---------------------------------------------------------------------------
// Bilinear data for (p,k), entry id e = k*64+p: row bases, x0, 4
// pre-multiplied corner weights.
// ---------------------------------------------------------------------------
struct TEnt { float4 a, b; };

__device__ __forceinline__ TEnt make_entry2(int e, float4 pk, int s0)
{
    const int p = e & 63;
    const int s = s0 + p;
    const int yi = s / WW;
    const int xi = s - yi * WW;
    const float py  = pk.y + (float)yi;
    const float pxf = pk.z + (float)xi;
    const float fy = floorf(py), fx = floorf(pxf);
    const float wy1 = py - fy, wx1 = pxf - fx;
    const float wy0 = 1.f - wy1, wx0 = 1.f - wx1;
    const int ix0 = (int)fx;
    const int iy0 = (int)fy, iy1 = iy0 + 1;
    const float vx0 = (ix0 >= 0 && ix0 < WW)      ? 1.f : 0.f;
    const float vx1 = (ix0 >= -1 && ix0 < WW - 1) ? 1.f : 0.f;
    const float vy0 = (iy0 >= 0 && iy0 < HH)      ? 1.f : 0.f;
    const float vy1 = (iy1 >= 0 && iy1 < HH)      ? 1.f : 0.f;
    const int yc0 = min(max(iy0, 0), HH - 1);
    const int yc1 = min(max(iy1, 0), HH - 1);
    TEnt r;
    r.a.x = __uint_as_float((unsigned)(yc0 * WW * 128));
    r.a.y = __uint_as_float((unsigned)(yc1 * WW * 128));
    r.a.z = __int_as_float(ix0);
    r.a.w = 0.f;
    const float ay0 = pk.x * wy0 * vy0;
    const float ay1 = pk.x * wy1 * vy1;
    r.b.x = ay0 * wx0 * vx0;
    r.b.y = ay0 * wx1 * vx1;
    r.b.z = ay1 * wx0 * vx0;
    r.b.w = ay1 * wx1 * vx1;
    return r;
}

// ---------------------------------------------------------------------------
// Fused, 64-px tiles: the per-block prologue (weight stage, query conv,
// softmax, T2 build) amortizes over 2x pixels; sampling per-px unchanged
// (R6 drain structure: 9-deep forced gather cluster, vmcnt(0), consume).
// Halved block count (1568) is the prologue ablation: if dur doesn't move,
// the sampling phase is TA-throughput-bound and 42us was never prologue.
// ---------------------------------------------------------------------------
__global__ __launch_bounds__(256, 4) void fused_sample_kernel(
    const float* __restrict__ query, const float* __restrict__ w_attn,
    const float* __restrict__ b_attn, const float* __restrict__ w_off,
    const float* __restrict__ b_off, const __half* __restrict__ Kf,
    float* __restrict__ out)
{
    __shared__ float S[SM_LDS];
    float*  Wq   = S + OFF_WQ;     // [64][20]
    float*  Sb   = S + OFF_SB;     // [20]
    float*  L    = S + OFF_L;      // [64][21]
    float*  Xq   = S + OFF_XQ;     // [64][64]
    float4* Pf4  = reinterpret_cast<float4*>(S + OFF_P);   // [576] {a,dy,dx,-}
    float*  Tb   = S + OFF_T;      // T2: 576 (p,k) x 4 corners x {addr,wgt}
    float*  OutT = S + OFF_OUTT;   // [64][68]

    const int t = threadIdx.x;
    const int l = t & 63;
    const int w = t >> 6;
    const int blk = blockIdx.x;
    const int b = blk & 7;                       // batch == XCD round-robin
    const int tile = blk >> 3;
    const int s0 = tile * SM_PX;
    const size_t qb = (size_t)b * CC * HWs + s0;
    const char* Kfb = reinterpret_cast<const char*>(Kf) + (size_t)b * HWs * 128;

    // ---- stage transposed query weights [k][20] + biases + query tile
    for (int f = t; f < 304; f += 256) {
        const int r = f >> 4;
        const int q = f & 15;
        const float* src = (r < KEYN) ? (w_attn + r * CC) : (w_off + (r - KEYN) * CC);
        const float4 wv = *reinterpret_cast<const float4*>(src + 4 * q);
        Wq[(4 * q + 0) * 20 + r] = wv.x;
        Wq[(4 * q + 1) * 20 + r] = wv.y;
        Wq[(4 * q + 2) * 20 + r] = wv.z;
        Wq[(4 * q + 3) * 20 + r] = wv.w;
    }
    if (t < 64) Wq[t * 20 + 19] = 0.f;
    if (t < 20) Sb[t] = (t < KEYN) ? b_attn[t] : (t < 19 ? b_off[t - KEYN] : 0.f);
    // Xq[c][0..63]: 4096 floats = 1024 float4, 4 per thread
    #pragma unroll
    for (int m = 0; m < 4; ++m) {
        const int f = t + 256 * m;          // 0..1023
        const int c = f >> 4;                // 0..63
        const int p4 = (f & 15) * 4;         // 0..60
        *reinterpret_cast<float4*>(&Xq[c * 64 + p4]) =
            *reinterpret_cast<const float4*>(query + qb + (size_t)c * HWs + p4);
    }
    __syncthreads();

    // ---- query conv: slots f < 320: px = f&63, og = f>>6 (0..4, 4 outs)
    {
        #pragma unroll
        for (int m = 0; m < 2; ++m) {
            const int f = t + 256 * m;
            if (m == 1 && t >= 64) break;      // slots 256..319 only
            const int px = f & 63;
            const int og = f >> 6;             // 0..4
            const int o4 = 4 * og;
            float4 acc = *reinterpret_cast<const float4*>(&Sb[o4]);
            #pragma unroll 8
            for (int k = 0; k < 64; ++k) {
                const float a = Xq[k * 64 + px];
                const float4 wv = *reinterpret_cast<const float4*>(&Wq[k * 20 + o4]);
                acc.x = fmaf(a, wv.x, acc.x);
                acc.y = fmaf(a, wv.y, acc.y);
                acc.z = fmaf(a, wv.z, acc.z);
                acc.w = fmaf(a, wv.w, acc.w);
            }
            L[px * 21 + o4 + 0] = acc.x;
            L[px * 21 + o4 + 1] = acc.y;
            L[px * 21 + o4 + 2] = acc.z;
            L[px * 21 + o4 + 3] = acc.w;
        }
    }
    __syncthreads();

    // ---- softmax + pack Pf[k*64+px] = {attn, dy, dx, 0} (overlays dead Xq)
    if (t < SM_PX) {
        float lg[KEYN], of[10];
        #pragma unroll
        for (int k = 0; k < KEYN; ++k) lg[k] = L[t * 21 + k];
        #pragma unroll
        for (int j = 0; j < 10; ++j) of[j] = L[t * 21 + KEYN + j];
        float m = lg[0];
        #pragma unroll
        for (int k = 1; k < KEYN; ++k) m = fmaxf(m, lg[k]);
        float s = 0.f, e[KEYN];
        #pragma unroll
        for (int k = 0; k < KEYN; ++k) { e[k] = expf(lg[k] - m); s += e[k]; }
        const float sinv = 1.0f / s;
        #pragma unroll
        for (int k = 0; k < KEYN; ++k)
            Pf4[k * 64 + t] = make_float4(e[k] * sinv, of[k], of[k + 1], 0.f);
    }
    __syncthreads();

    // ---- build T2: entries e = t, t+256, (t<64) t+512. Read Pf to regs,
    // barrier, write corner records at (p*9+k)*8 + corner*2.
    {
        const float4 q1 = Pf4[t];
        const float4 q2 = Pf4[t + 256];
        float4 q3 = make_float4(0.f, 0.f, 0.f, 0.f);
        if (t < 64) q3 = Pf4[t + 512];
        __syncthreads();
        #pragma unroll
        for (int m = 0; m < 3; ++m) {
            if (m == 2 && t >= 64) break;
            const int e = t + 256 * m;
            const float4 qv = (m == 0) ? q1 : (m == 1) ? q2 : q3;
            const TEnt en = make_entry2(e, qv, s0);
            const int p = e & 63, k = e >> 6;
            const int x0 = __float_as_int(en.a.z);
            const unsigned xc0 = (unsigned)(min(max(x0, 0), WW - 1)) << 7;
            const unsigned xc1 = (unsigned)(min(max(x0 + 1, 0), WW - 1)) << 7;
            const unsigned rb0 = __float_as_uint(en.a.x);
            const unsigned rb1 = __float_as_uint(en.a.y);
            float4 r0, r1;
            r0.x = __uint_as_float(rb0 + xc0); r0.y = en.b.x;   // (y0,x0)
            r0.z = __uint_as_float(rb0 + xc1); r0.w = en.b.y;   // (y0,x1)
            r1.x = __uint_as_float(rb1 + xc0); r1.y = en.b.z;   // (y1,x0)
            r1.z = __uint_as_float(rb1 + xc1); r1.w = en.b.w;   // (y1,x1)
            float* dst = Tb + (p * 9 + k) * 8;
            *reinterpret_cast<float4*>(dst)     = r0;
            *reinterpret_cast<float4*>(dst + 4) = r1;
        }
    }
    __syncthreads();

    // ---- sampling: wave w -> px [16w,16w+16) as 8 rounds of a pixel pair.
    // Lane = (sub=l>>5 pixel, corner=(l>>3)&3, ch8=l&7).
    const int  ch8  = l & 7;                  // 8-channel chunk
    const int  corf = ((l >> 3) & 3) * 2;     // corner float offset in T2
    const int  sub  = l >> 5;                 // which pixel of the pair
    const char* KfbC = Kfb + (unsigned)(ch8 * 16);

    for (int j = 0; j < 8; ++j) {
        const int p = w * 16 + 2 * j + sub;
        const float* Te = Tb + p * 72 + corf;     // + k*8 per key

        // 9 broadcast b64 reads: {addr, wgt} per (p,k,corner)
        float2 tw[KEYN];
        #pragma unroll
        for (int k = 0; k < KEYN; ++k)
            tw[k] = *reinterpret_cast<const float2*>(Te + k * 8);

        // 9 forced-cluster gathers (16B each); all dests live at the wait
        v4i rr[KEYN];
        #pragma unroll
        for (int k = 0; k < KEYN; ++k)
            GLOAD(rr[k], KfbC + __float_as_uint(tw[k].x));
        asm volatile("s_waitcnt vmcnt(0)" ::: "memory");
        __builtin_amdgcn_sched_barrier(0);

        float acc[8] = {0.f, 0.f, 0.f, 0.f, 0.f, 0.f, 0.f, 0.f};
        #pragma unroll
        for (int k = 0; k < KEYN; ++k) {
            const float wgt = tw[k].y;
            union { int i; __half2 h; } u0, u1, u2, u3;
            u0.i = rr[k][0]; u1.i = rr[k][1]; u2.i = rr[k][2]; u3.i = rr[k][3];
            acc[0] = fmaf(__low2float(u0.h),  wgt, acc[0]);
            acc[1] = fmaf(__high2float(u0.h), wgt, acc[1]);
            acc[2] = fmaf(__low2float(u1.h),  wgt, acc[2]);
            acc[3] = fmaf(__high2float(u1.h), wgt, acc[3]);
            acc[4] = fmaf(__low2float(u2.h),  wgt, acc[4]);
            acc[5] = fmaf(__high2float(u2.h), wgt, acc[5]);
            acc[6] = fmaf(__low2float(u3.h),  wgt, acc[6]);
            acc[7] = fmaf(__high2float(u3.h), wgt, acc[7]);
        }

        // fold y-corner pairs (lane^16), then x-corner pairs (lane^8)
        #pragma unroll
        for (int i = 0; i < 8; ++i) acc[i] += swzx16(acc[i]);
        #pragma unroll
        for (int i = 0; i < 8; ++i) acc[i] += swzx8(acc[i]);

        if ((l & 24) == 0) {
            float* d = OutT + p * 68 + ch8 * 8;
            *reinterpret_cast<float4*>(d)     = make_float4(acc[0], acc[1], acc[2], acc[3]);
            *reinterpret_cast<float4*>(d + 4) = make_float4(acc[4], acc[5], acc[6], acc[7]);
        }
    }
    __syncthreads();

    // ---- transposed store: out[b][c][s0+px], 4096 elems / 256 threads
    const size_t ob = (size_t)b * CC * HWs + s0;
    #pragma unroll
    for (int m = 0; m < 16; ++m) {
        const int f = t + 256 * m;
        const int c = f >> 6;
        const int px = f & 63;
        out[ob + (size_t)c * HWs + px] = OutT[px * 68 + c];
    }
}

extern "C" void kernel_launch(void* const* d_in, const int* in_sizes, int n_in,
                              void* d_out, int out_size, void* d_ws, size_t ws_size,
                              hipStream_t stream)
{
    const float* query   = (const float*)d_in[0];
    const float* key     = (const float*)d_in[1];
    const float* w_refer = (const float*)d_in[2];
    const float* b_refer = (const float*)d_in[3];
    const float* w_attn  = (const float*)d_in[4];
    const float* b_attn  = (const float*)d_in[5];
    const float* w_off   = (const float*)d_in[6];
    const float* b_off   = (const float*)d_in[7];
    float* out = (float*)d_out;

    __half* Kf = (__half*)d_ws;   // [B*HW][64] pixel-major fp16, 12.8 MB

    hipLaunchKernelGGL(conv_key_kernel, dim3(CK2_NBLK), dim3(256), 0, stream,
                       key, w_refer, b_refer, Kf);
    hipLaunchKernelGGL(fused_sample_kernel, dim3(SM_NBLK), dim3(256), 0, stream,
                       query, w_attn, b_attn, w_off, b_off, Kf, out);
}

// Round 15
// 138.532 us; speedup vs baseline: 1.0798x; 1.0736x over previous
//
#include <hip/hip_runtime.h>
#include <hip/hip_fp16.h>

#define BB 8
#define CC 64
#define HH 112
#define WW 112
#define HWs (HH * WW)                 // 12544
#define KEYN 9

// ---- conv_key MFMA geometry: 128-px tile, 4 waves, 16x16x32_f16 ----
#define CKM_PX 128
#define CKM_TILES (HWs / CKM_PX)      // 98
#define CKM_NBLK (BB * CKM_TILES)     // 784
#define WTH 72                        // Wt fp16 row stride (144B: 16B-aligned,
                                      // 4o mod 32 bank spread -> 2-way free)

// ---- fused sampler geometry (R9-proven, fused = 42.0 us) ----
#define SM_PX 32
#define SM_TILES (HWs / SM_PX)        // 392
#define SM_NBLK (BB * SM_TILES)       // 3136

// fused-kernel LDS float offsets (phase overlays):
//   phase A (stage+conv):   Wq[64][20] @0, Sb[20] @1280, L[32][21] @1300,
//                           Xq[64][32] @1972 (end 4020)
//   phase B (softmax):      Pf float4 [288] @0 (overlays dead Wq)
//   phase C (sampling):     T2 [32px][9k][4corner]{addr,wgt} @0 (2304 f),
//                           OutT[32][68] @2304
#define OFF_WQ   0
#define OFF_SB   1280
#define OFF_L    1300
#define OFF_XQ   1972
#define OFF_P    0
#define OFF_T    0
#define OFF_OUTT 2304
#define SM_LDS   4480                 // 17.92 KB

typedef int   v4i __attribute__((ext_vector_type(4)));
typedef float v4f __attribute__((ext_vector_type(4)));
typedef _Float16 v8h __attribute__((ext_vector_type(8)));

// forced-MLP gather: result register is bound by asm -> must stay live
#define GLOAD(dst, p) asm volatile("global_load_dwordx4 %0, %1, off" \
                                   : "=&v"(dst) : "v"(p))

// xor lane swaps within 32-lane halves (BitMode: offset=(xor<<10)|0x1F)
__device__ __forceinline__ float swzx16(float v) {
    return __uint_as_float(__builtin_amdgcn_ds_swizzle(__float_as_uint(v), 0x401F));
}
__device__ __forceinline__ float swzx8(float v) {
    return __uint_as_float(__builtin_amdgcn_ds_swizzle(__float_as_uint(v), 0x201F));
}

// ---------------------------------------------------------------------------
// conv_key v3 (MFMA): Kf[b*HW+px][64] = half(W_refer @ key + b_refer).
// Per-wave: D[o=16][px=16] tiles via v_mfma_f32_16x16x32_f16.
//   A = W fragment: row=o=(l&15), k=(l>>4)*8+j -> contiguous 16B ds_read_b128
//       from fp16 Wt[o][k] (72-half padded rows).
//   B = key fragment: col=px=(l&15), k=(l>>4)*8+j -> 8 k-strided scalar
//       global loads (16-lane px-coalesced) + cvt f32->f16.
//   D lane layout: px=(l&15), o=(l>>4)*4+reg -> 4 consecutive o = 8B store.
// Wave w covers px [32w,32w+32): 4 o-tiles x 2 px-tiles x 2 K-steps =
// 16 MFMA. Bias init via float4. LDS = 9.2 KB. BATCH-PINNED (b=blk&7):
// Kf dirty in XCD b's L2 for the pinned sampler (R6/R8/R9 quantified).
// ---------------------------------------------------------------------------
__global__ __launch_bounds__(256, 4) void conv_key_kernel(
    const float* __restrict__ key, const float* __restrict__ w_refer,
    const float* __restrict__ b_refer, __half* __restrict__ Kf)
{
    __shared__ __half Wt[64 * WTH];      // 9.2 KB fp16 [o][k]

    const int t = threadIdx.x;
    const int blk = blockIdx.x;
    const int b = blk & 7;                       // batch == XCD round-robin
    const int s0 = (blk >> 3) * CKM_PX;
    const size_t inb = (size_t)b * CC * HWs + s0;

    // ---- stage Wt fp16 [o][k], rows padded to 72 halfs
    #pragma unroll
    for (int m = 0; m < 4; ++m) {
        const int f = t + 256 * m;
        const int o = f >> 4;
        const int q = f & 15;
        const float4 wv = *reinterpret_cast<const float4*>(w_refer + o * CC + 4 * q);
        __half2* dst = reinterpret_cast<__half2*>(&Wt[o * WTH + 4 * q]);
        dst[0] = __floats2half2_rn(wv.x, wv.y);
        dst[1] = __floats2half2_rn(wv.z, wv.w);
    }
    __syncthreads();

    const int l  = t & 63;
    const int w  = t >> 6;
    const int lo = l & 15;      // A-row (o) / B-col (px) low index
    const int hi = l >> 4;      // 0..3: k-group / D-row group
    const int px0 = w * 32;

    // ---- A fragments (weights): 4 o-tiles x 2 K-steps, ds_read_b128 each
    v8h aW[4][2];
    #pragma unroll
    for (int ot = 0; ot < 4; ++ot)
        #pragma unroll
        for (int ks = 0; ks < 2; ++ks)
            aW[ot][ks] = *reinterpret_cast<const v8h*>(
                &Wt[(ot * 16 + lo) * WTH + ks * 32 + hi * 8]);

    // ---- B fragments (key): 2 px-tiles x 2 K-steps, 8 scalar loads each
    v8h bK[2][2];
    #pragma unroll
    for (int pt = 0; pt < 2; ++pt) {
        const int px = px0 + pt * 16 + lo;
        #pragma unroll
        for (int ks = 0; ks < 2; ++ks) {
            const float* kp = key + inb + (size_t)(ks * 32 + hi * 8) * HWs + px;
            v8h bb;
            #pragma unroll
            for (int j = 0; j < 8; ++j)
                bb[j] = (_Float16)kp[(size_t)j * HWs];
            bK[pt][ks] = bb;
        }
    }

    // ---- MFMA accumulate (bias-init) + 8B fp16 stores
    #pragma unroll
    for (int ot = 0; ot < 4; ++ot) {
        const float4 bv = *reinterpret_cast<const float4*>(b_refer + ot * 16 + hi * 4);
        #pragma unroll
        for (int pt = 0; pt < 2; ++pt) {
            v4f c;
            c[0] = bv.x; c[1] = bv.y; c[2] = bv.z; c[3] = bv.w;
            c = __builtin_amdgcn_mfma_f32_16x16x32_f16(aW[ot][0], bK[pt][0], c, 0, 0, 0);
            c = __builtin_amdgcn_mfma_f32_16x16x32_f16(aW[ot][1], bK[pt][1], c, 0, 0, 0);
            const int px = px0 + pt * 16 + lo;
            const size_t ob = ((size_t)b * HWs + s0 + px) * CC + ot * 16 + hi * 4;
            union { __half2 h[2]; float2 f; } u;
            u.h[0] = __floats2half2_rn(c[0], c[1]);
            u.h[1] = __floats2half2_rn(c[2], c[3]);
            *reinterpret_cast<float2*>(Kf + ob) = u.f;   // 8B, aligned
        }
    }
}

// ---------------------------------------------------------------------------
// Bilinear data for (p,k): row bases, x0, 4 pre-multiplied corner weights.
// ---------------------------------------------------------------------------
struct TEnt { float4 a, b; };

__device__ __forceinline__ TEnt make_entry2(int e, float4 pk, int s0)
{
    const int p = e & 31;
    const int s = s0 + p;
    const int yi = s / WW;
    const int xi = s - yi * WW;
    const float py  = pk.y + (float)yi;
    const float pxf = pk.z + (float)xi;
    const float fy = floorf(py), fx = floorf(pxf);
    const float wy1 = py - fy, wx1 = pxf - fx;
    const float wy0 = 1.f - wy1, wx0 = 1.f - wx1;
    const int ix0 = (int)fx;
    const int iy0 = (int)fy, iy1 = iy0 + 1;
    const float vx0 = (ix0 >= 0 && ix0 < WW)      ? 1.f : 0.f;
    const float vx1 = (ix0 >= -1 && ix0 < WW - 1) ? 1.f : 0.f;
    const float vy0 = (iy0 >= 0 && iy0 < HH)      ? 1.f : 0.f;
    const float vy1 = (iy1 >= 0 && iy1 < HH)      ? 1.f : 0.f;
    const int yc0 = min(max(iy0, 0), HH - 1);
    const int yc1 = min(max(iy1, 0), HH - 1);
    TEnt r;
    r.a.x = __uint_as_float((unsigned)(yc0 * WW * 128));
    r.a.y = __uint_as_float((unsigned)(yc1 * WW * 128));
    r.a.z = __int_as_float(ix0);
    r.a.w = 0.f;
    const float ay0 = pk.x * wy0 * vy0;
    const float ay1 = pk.x * wy1 * vy1;
    r.b.x = ay0 * wx0 * vx0;
    r.b.y = ay0 * wx1 * vx1;
    r.b.z = ay1 * wx0 * vx0;
    r.b.w = ay1 * wx1 * vx1;
    return r;
}

// ---------------------------------------------------------------------------
// Fused (R9-proven, 42.0 us): query conv -> softmax -> pre-selected corner
// table T2[p][k][corner] = {addr, wgt} -> 9-deep forced gather cluster per
// round (asm loads, vmcnt(0), fence, consume). Frozen after 7 structural
// variants all landed 42+-1.5 us.
// ---------------------------------------------------------------------------
__global__ __launch_bounds__(256, 4) void fused_sample_kernel(
    const float* __restrict__ query, const float* __restrict__ w_attn,
    const float* __restrict__ b_attn, const float* __restrict__ w_off,
    const float* __restrict__ b_off, const __half* __restrict__ Kf,
    float* __restrict__ out)
{
    __shared__ float S[SM_LDS];
    float*  Wq   = S + OFF_WQ;     // [64][20]
    float*  Sb   = S + OFF_SB;     // [20]
    float*  L    = S + OFF_L;      // [32][21]
    float*  Xq   = S + OFF_XQ;     // [64][32]
    float4* Pf4  = reinterpret_cast<float4*>(S + OFF_P);   // [288] {a,dy,dx,-}
    float*  Tb   = S + OFF_T;      // T2: 288 (p,k) x 4 corners x {addr,wgt}
    float*  OutT = S + OFF_OUTT;   // [32][68]

    const int t = threadIdx.x;
    const int l = t & 63;
    const int w = t >> 6;
    const int blk = blockIdx.x;
    const int b = blk & 7;                       // batch == XCD round-robin
    const int tile = blk >> 3;
    const int s0 = tile * SM_PX;
    const size_t qb = (size_t)b * CC * HWs + s0;
    const char* Kfb = reinterpret_cast<const char*>(Kf) + (size_t)b * HWs * 128;

    // ---- stage transposed query weights [k][20] + biases + query tile
    for (int f = t; f < 304; f += 256) {
        const int r = f >> 4;
        const int q = f & 15;
        const float* src = (r < KEYN) ? (w_attn + r * CC) : (w_off + (r - KEYN) * CC);
        const float4 wv = *reinterpret_cast<const float4*>(src + 4 * q);
        Wq[(4 * q + 0) * 20 + r] = wv.x;
        Wq[(4 * q + 1) * 20 + r] = wv.y;
        Wq[(4 * q + 2) * 20 + r] = wv.z;
        Wq[(4 * q + 3) * 20 + r] = wv.w;
    }
    if (t < 64) Wq[t * 20 + 19] = 0.f;
    if (t < 20) Sb[t] = (t < KEYN) ? b_attn[t] : (t < 19 ? b_off[t - KEYN] : 0.f);
    #pragma unroll
    for (int m = 0; m < 2; ++m) {
        const int f = t + 256 * m;          // 0..511
        const int c = f >> 3;                // 0..63
        const int p4 = (f & 7) * 4;          // 0..28
        *reinterpret_cast<float4*>(&Xq[c * 32 + p4]) =
            *reinterpret_cast<const float4*>(query + qb + (size_t)c * HWs + p4);
    }
    __syncthreads();

    // ---- query conv: thread = (px = t&31, og = t>>5 < 5); input from LDS
    {
        const int px = t & 31;
        const int og = t >> 5;
        if (og < 5) {
            const int o4 = 4 * og;
            float4 acc = *reinterpret_cast<const float4*>(&Sb[o4]);
            #pragma unroll 8
            for (int k = 0; k < 64; ++k) {
                const float a = Xq[k * 32 + px];
                const float4 wv = *reinterpret_cast<const float4*>(&Wq[k * 20 + o4]);
                acc.x = fmaf(a, wv.x, acc.x);
                acc.y = fmaf(a, wv.y, acc.y);
                acc.z = fmaf(a, wv.z, acc.z);
                acc.w = fmaf(a, wv.w, acc.w);
            }
            L[px * 21 + o4 + 0] = acc.x;
            L[px * 21 + o4 + 1] = acc.y;
            L[px * 21 + o4 + 2] = acc.z;
            L[px * 21 + o4 + 3] = acc.w;
        }
    }
    __syncthreads();

    // ---- softmax + pack Pf[k*32+px] = {attn, dy, dx, 0} (overlays dead Wq)
    if (t < SM_PX) {
        float lg[KEYN], of[10];
        #pragma unroll
        for (int k = 0; k < KEYN; ++k) lg[k] = L[t * 21 + k];
        #pragma unroll
        for (int j = 0; j < 10; ++j) of[j] = L[t * 21 + KEYN + j];
        float m = lg[0];
        #pragma unroll
        for (int k = 1; k < KEYN; ++k) m = fmaxf(m, lg[k]);
        float s = 0.f, e[KEYN];
        #pragma unroll
        for (int k = 0; k < KEYN; ++k) { e[k] = expf(lg[k] - m); s += e[k]; }
        const float sinv = 1.0f / s;
        #pragma unroll
        for (int k = 0; k < KEYN; ++k)
            Pf4[k * 32 + t] = make_float4(e[k] * sinv, of[k], of[k + 1], 0.f);
    }
    __syncthreads();

    // ---- build T2: entry e = k*32+p -> 4 corner records at float index
    // (p*9+k)*8 + corner*2: {addr = rowbase + clamp(x0+c2)*128, wgt}.
    {
        const float4 q1 = Pf4[t];
        float4 q2 = make_float4(0.f, 0.f, 0.f, 0.f);
        if (t < 32) q2 = Pf4[256 + t];
        __syncthreads();
        #pragma unroll
        for (int m = 0; m < 2; ++m) {
            const int e = (m == 0) ? t : (256 + t);
            if (m == 1 && t >= 32) break;
            const TEnt en = make_entry2(e, (m == 0) ? q1 : q2, s0);
            const int p = e & 31, k = e >> 5;
            const int x0 = __float_as_int(en.a.z);
            const unsigned xc0 = (unsigned)(min(max(x0, 0), WW - 1)) << 7;
            const unsigned xc1 = (unsigned)(min(max(x0 + 1, 0), WW - 1)) << 7;
            const unsigned rb0 = __float_as_uint(en.a.x);
            const unsigned rb1 = __float_as_uint(en.a.y);
            float4 r0, r1;
            r0.x = __uint_as_float(rb0 + xc0); r0.y = en.b.x;   // (y0,x0)
            r0.z = __uint_as_float(rb0 + xc1); r0.w = en.b.y;   // (y0,x1)
            r1.x = __uint_as_float(rb1 + xc0); r1.y = en.b.z;   // (y1,x0)
            r1.z = __uint_as_float(rb1 + xc1); r1.w = en.b.w;   // (y1,x1)
            float* dst = Tb + (p * 9 + k) * 8;
            *reinterpret_cast<float4*>(dst)     = r0;
            *reinterpret_cast<float4*>(dst + 4) = r1;
        }
    }
    __syncthreads();

    // ---- sampling: wave w -> px [8w,8w+8) as 4 rounds of a pixel pair.
    // Lane = (sub=l>>5 pixel, corner=(l>>3)&3, ch8=l&7).
    const int  ch8  = l & 7;                  // 8-channel chunk
    const int  corf = ((l >> 3) & 3) * 2;     // corner float offset in T2
    const int  sub  = l >> 5;                 // which pixel of the pair
    const char* KfbC = Kfb + (unsigned)(ch8 * 16);

    for (int j = 0; j < 4; ++j) {
        const int p = w * 8 + 2 * j + sub;
        const float* Te = Tb + p * 72 + corf;     // + k*8 per key

        // 9 broadcast b64 reads: {addr, wgt} per (p,k,corner)
        float2 tw[KEYN];
        #pragma unroll
        for (int k = 0; k < KEYN; ++k)
            tw[k] = *reinterpret_cast<const float2*>(Te + k * 8);

        // 9 forced-cluster gathers (16B each); all dests live at the wait
        v4i rr[KEYN];
        #pragma unroll
        for (int k = 0; k < KEYN; ++k)
            GLOAD(rr[k], KfbC + __float_as_uint(tw[k].x));
        asm volatile("s_waitcnt vmcnt(0)" ::: "memory");
        __builtin_amdgcn_sched_barrier(0);

        float acc[8] = {0.f, 0.f, 0.f, 0.f, 0.f, 0.f, 0.f, 0.f};
        #pragma unroll
        for (int k = 0; k < KEYN; ++k) {
            const float wgt = tw[k].y;
            union { int i; __half2 h; } u0, u1, u2, u3;
            u0.i = rr[k][0]; u1.i = rr[k][1]; u2.i = rr[k][2]; u3.i = rr[k][3];
            acc[0] = fmaf(__low2float(u0.h),  wgt, acc[0]);
            acc[1] = fmaf(__high2float(u0.h), wgt, acc[1]);
            acc[2] = fmaf(__low2float(u1.h),  wgt, acc[2]);
            acc[3] = fmaf(__high2float(u1.h), wgt, acc[3]);
            acc[4] = fmaf(__low2float(u2.h),  wgt, acc[4]);
            acc[5] = fmaf(__high2float(u2.h), wgt, acc[5]);
            acc[6] = fmaf(__low2float(u3.h),  wgt, acc[6]);
            acc[7] = fmaf(__high2float(u3.h), wgt, acc[7]);
        }

        // fold y-corner pairs (lane^16), then x-corner pairs (lane^8)
        #pragma unroll
        for (int i = 0; i < 8; ++i) acc[i] += swzx16(acc[i]);
        #pragma unroll
        for (int i = 0; i < 8; ++i) acc[i] += swzx8(acc[i]);

        if ((l & 24) == 0) {
            float* d = OutT + p * 68 + ch8 * 8;
            *reinterpret_cast<float4*>(d)     = make_float4(acc[0], acc[1], acc[2], acc[3]);
            *reinterpret_cast<float4*>(d + 4) = make_float4(acc[4], acc[5], acc[6], acc[7]);
        }
    }
    __syncthreads();

    // ---- transposed store: out[b][c][s0+px]
    const size_t ob = (size_t)b * CC * HWs + s0;
    #pragma unroll
    for (int m = 0; m < 8; ++m) {
        const int f = t + 256 * m;
        const int c = f >> 5;
        const int px = f & 31;
        out[ob + (size_t)c * HWs + px] = OutT[px * 68 + c];
    }
}

extern "C" void kernel_launch(void* const* d_in, const int* in_sizes, int n_in,
                              void* d_out, int out_size, void* d_ws, size_t ws_size,
                              hipStream_t stream)
{
    const float* query   = (const float*)d_in[0];
    const float* key     = (const float*)d_in[1];
    const float* w_refer = (const float*)d_in[2];
    const float* b_refer = (const float*)d_in[3];
    const float* w_attn  = (const float*)d_in[4];
    const float* b_attn  = (const float*)d_in[5];
    const float* w_off   = (const float*)d_in[6];
    const float* b_off   = (const float*)d_in[7];
    float* out = (float*)d_out;

    __half* Kf = (__half*)d_ws;   // [B*HW][64] pixel-major fp16, 12.8 MB

    hipLaunchKernelGGL(conv_key_kernel, dim3(CKM_NBLK), dim3(256), 0, stream,
                       key, w_refer, b_refer, Kf);
    hipLaunchKernelGGL(fused_sample_kernel, dim3(SM_NBLK), dim3(256), 0, stream,
                       query, w_attn, b_attn, w_off, b_off, Kf, out);
}